// Round 3
// baseline (558.734 us; speedup 1.0000x reference)
//
#include <hip/hip_runtime.h>

// GraphConvolution on MI355X (gfx950) — full-integer i8 pipeline.
//
// Algebra: Xq/act_delta = m in [0,15] (i8), Wq/wgt_delta in [-7,7] (i8),
// Sq/sup_delta = m2 in [0,15] (i8). Both matmuls are exact in i32. Only the
// adj->i8 quantization (scale 127) introduces error (~1 bf16-ULP of output).
//
// Time model (verified across rounds 0-2 vs counters): harness re-poison
// fills ~330us fixed; our code ~222us of which GEMM2 ~140us at ~25% of the
// 3944-TOPS i8 ceiling (compute floor 35us).
//
// Round-6 (this round): GEMM2 ported to the 8-phase-class structure
// (T3+T4+T5 on top of T2), per the regime-gate evidence that counted-vmcnt
// is the lever past the 2-phase ceiling:
//   - 256x256 tile, 512 thr = 8 waves (2M x 4N), per-wave 128x64 out.
//   - TRIPLE-buffered LDS (3 x 32KB = 96KB, 1 block/CU): depth-2 prefetch so
//     the tile-boundary wait is vmcnt(4) (newest tile's 4 loads stay in
//     flight) instead of a drain-to-0. Write target = buffer last read two
//     tiles ago; the single boundary s_barrier per tile makes that safe.
//   - Raw __builtin_amdgcn_s_barrier + asm s_waitcnt (NOT __syncthreads,
//     which force-drains vmcnt(0) and killed prior pipelining attempts).
//   - setprio(1) around each 8-MFMA cluster (T5 pays only in this regime).
//   - Same BK=64 row format, same T2 swizzle constants (measured 0 bank
//     conflicts), same MFMA/fragment math, same atomic-f32 epilogue as the
//     verified 2-phase kernel -> minimal new correctness surface.
// GEMM1 stays on the 2-phase body: its dispatch is adjq-BW-bound anyway.
//
// Round-5 learnings kept: no device-scope fences in hot kernels (L2
// writeback/invalidate disaster, round-4); split-K via f32 atomicAdd into
// pre-zeroed out (exact: |acc| < 2^24; commutative -> deterministic);
// pre(wstats|xquant) fusion; gemm1|adjq z-fusion.
//
// Grid congruence: linear_id mod 8 == bx mod 8 for all (y,z) sharing an
// m-strip (32*y, 128*z both ≡ 0 mod 8) -> same XCD/L2 for shared adj strips.

#define AS_G __attribute__((address_space(1)))
#define AS_L __attribute__((address_space(3)))

typedef int i32x4 __attribute__((ext_vector_type(4)));
typedef char c8 __attribute__((ext_vector_type(8)));
typedef char c16 __attribute__((ext_vector_type(16)));

static __device__ __forceinline__ void gload_lds16(const char* g, char* l) {
  __builtin_amdgcn_global_load_lds((const AS_G unsigned int*)g,
                                   (AS_L unsigned int*)l, 16, 0, 0);
}

// ---- fused: wstats (blocks 0..255, f64 atomics) + xquant (blocks 256..) ----
__global__ void pre_kernel(const float* __restrict__ w, double* __restrict__ stats,
                           const float* __restrict__ x, char* __restrict__ xq,
                           const float* __restrict__ alpha_p, int wn, int xn) {
  if (blockIdx.x < 256) {
    double s = 0.0, ss = 0.0;
    for (int i = (blockIdx.x * 256 + threadIdx.x) * 4; i < wn; i += 256 * 256 * 4) {
      float4 v = *(const float4*)&w[i];
      s += (double)v.x + (double)v.y + (double)v.z + (double)v.w;
      ss += (double)v.x * v.x + (double)v.y * v.y + (double)v.z * v.z + (double)v.w * v.w;
    }
#pragma unroll
    for (int off = 32; off > 0; off >>= 1) {
      s  += __shfl_down(s, off);
      ss += __shfl_down(ss, off);
    }
    if ((threadIdx.x & 63) == 0) {
      atomicAdd(&stats[0], s);
      atomicAdd(&stats[1], ss);
    }
  } else {
    int i = ((blockIdx.x - 256) * 256 + threadIdx.x) * 8;
    if (i >= xn) return;
    const float alpha = *alpha_p;
    float4 v0 = *(const float4*)&x[i];
    float4 v1 = *(const float4*)&x[i + 4];
    c8 o;
    o[0] = (char)(int)rintf(fminf(v0.x / alpha, 1.f) * 15.f);
    o[1] = (char)(int)rintf(fminf(v0.y / alpha, 1.f) * 15.f);
    o[2] = (char)(int)rintf(fminf(v0.z / alpha, 1.f) * 15.f);
    o[3] = (char)(int)rintf(fminf(v0.w / alpha, 1.f) * 15.f);
    o[4] = (char)(int)rintf(fminf(v1.x / alpha, 1.f) * 15.f);
    o[5] = (char)(int)rintf(fminf(v1.y / alpha, 1.f) * 15.f);
    o[6] = (char)(int)rintf(fminf(v1.z / alpha, 1.f) * 15.f);
    o[7] = (char)(int)rintf(fminf(v1.w / alpha, 1.f) * 15.f);
    *(c8*)&xq[i] = o;
  }
}

// ------------- weight quant -> i8 levels, transposed (OUTF x INF) -------------
__global__ void wquant_kernel(const float* __restrict__ w, char* __restrict__ wt,
                              const double* __restrict__ stats,
                              const float* __restrict__ alpha_p) {
  int idx = blockIdx.x * 256 + threadIdx.x;
  const double cnt = 1048576.0;
  const double mean = stats[0] / cnt;
  const double var = (stats[1] - stats[0] * mean) / (cnt - 1.0);  // ddof=1
  const float meanf = (float)mean;
  const float stdf = (float)sqrt(var);
  const float alpha = *alpha_p;
  const int n = idx >> 10;          // out-feature
  const int k = idx & 1023;         // in-feature
  float wn = (w[(size_t)k * 1024 + n] - meanf) / stdf;
  float wc = fminf(fmaxf(wn / alpha, -1.f), 1.f);
  wt[idx] = (char)(int)copysignf(rintf(fabsf(wc) * 7.f), wc);  // -7..7
}

// ---------------- 2-phase i8 GEMM body (GEMM1 + AF32 fallback) ----------------
// RELUQ: epilogue scale*relu*quant -> i8, store transposed Ct[N][M].
// else : split-K: epilogue atomicAdd((float)acc * sc) into pre-zeroed f32 out.
// T2 swizzle: LDS(row, c) holds Global(row, (c - (row>>1))&3).
template <bool RELUQ, bool AF32>
static __device__ __forceinline__ void gemm_body(
    const void* __restrict__ Av, const char* __restrict__ B, void* __restrict__ Cv,
    float* __restrict__ outp,
    const int M, const int N, const int LDK, const int Kspan, const int zidx,
    const float* s0p, const float* s1p, const float* s2p) {
  __shared__ __align__(16) char As[2][128 * 64];
  __shared__ __align__(16) char Bs[2][128 * 64];

  const int tid = threadIdx.x;
  const int lane = tid & 63;
  const int wv = tid >> 6;
  const int wm = wv >> 1, wn = wv & 1;
  const int m0 = blockIdx.x * 128, n0 = blockIdx.y * 128;
  const int kz = zidx * Kspan;

  const int srow = tid >> 2;
  const int scol = (((tid & 3) + 4 - ((tid >> 3) & 3)) & 3) * 16;
  const int frow = tid >> 1;
  const int ft = (tid & 1) * 2;
  const int fsh = (tid >> 2) & 3;

  i32x4 acc[4][4];
#pragma unroll
  for (int i = 0; i < 4; ++i)
#pragma unroll
    for (int j = 0; j < 4; ++j) acc[i][j] = (i32x4){0, 0, 0, 0};

  const int lrow = lane & 15;
  const int q16 = (((lane >> 4) + (lrow >> 1)) & 3) * 16;

  auto stage = [&](int b, int kt) {
    if (AF32) {
      const float* Af = (const float*)Av;
      const float* src = Af + (size_t)(m0 + frow) * LDK + kt + (tid & 1) * 32;
      c16 p0, p1;
#pragma unroll
      for (int j = 0; j < 4; ++j) {
        float4 v = *(const float4*)(src + 4 * j);
        p0[4 * j + 0] = (char)(int)rintf(v.x * 127.f);
        p0[4 * j + 1] = (char)(int)rintf(v.y * 127.f);
        p0[4 * j + 2] = (char)(int)rintf(v.z * 127.f);
        p0[4 * j + 3] = (char)(int)rintf(v.w * 127.f);
      }
#pragma unroll
      for (int j = 0; j < 4; ++j) {
        float4 v = *(const float4*)(src + 16 + 4 * j);
        p1[4 * j + 0] = (char)(int)rintf(v.x * 127.f);
        p1[4 * j + 1] = (char)(int)rintf(v.y * 127.f);
        p1[4 * j + 2] = (char)(int)rintf(v.z * 127.f);
        p1[4 * j + 3] = (char)(int)rintf(v.w * 127.f);
      }
      *(c16*)&As[b][frow * 64 + (((ft + 0) + fsh) & 3) * 16] = p0;
      *(c16*)&As[b][frow * 64 + (((ft + 1) + fsh) & 3) * 16] = p1;
    } else {
      const char* Ab = (const char*)Av;
      gload_lds16(Ab + (size_t)(m0 + srow) * LDK + kt + scol, &As[b][wv * 1024]);
      gload_lds16(Ab + (size_t)(m0 + 64 + srow) * LDK + kt + scol,
                  &As[b][4096 + wv * 1024]);
    }
    gload_lds16(B + (size_t)(n0 + srow) * LDK + kt + scol, &Bs[b][wv * 1024]);
    gload_lds16(B + (size_t)(n0 + 64 + srow) * LDK + kt + scol,
                &Bs[b][4096 + wv * 1024]);
  };

  const int nt = Kspan / 64;
  stage(0, kz);
  __syncthreads();

  for (int t = 0; t < nt; ++t) {
    const int cur = t & 1;
    if (t + 1 < nt) stage(cur ^ 1, kz + (t + 1) * 64);

    i32x4 af[4], bfr[4];
#pragma unroll
    for (int mi = 0; mi < 4; ++mi)
      af[mi] = *(const i32x4*)&As[cur][(wm * 64 + mi * 16 + lrow) * 64 + q16];
#pragma unroll
    for (int ni = 0; ni < 4; ++ni)
      bfr[ni] = *(const i32x4*)&Bs[cur][(wn * 64 + ni * 16 + lrow) * 64 + q16];
#pragma unroll
    for (int mi = 0; mi < 4; ++mi)
#pragma unroll
      for (int ni = 0; ni < 4; ++ni)
        acc[mi][ni] =
            __builtin_amdgcn_mfma_i32_16x16x64_i8(af[mi], bfr[ni], acc[mi][ni], 0, 0, 0);

    __syncthreads();
  }

  const int qr = (lane >> 4) * 4;
  if (RELUQ) {
    const float d_act = *s0p / 15.f;
    const float d_wgt = *s1p / 7.f;
    const float a2 = *s2p;
    char* Ct = (char*)Cv;  // N x M i8
#pragma unroll
    for (int mi = 0; mi < 4; ++mi) {
      const int mb = m0 + wm * 64 + mi * 16 + qr;
#pragma unroll
      for (int ni = 0; ni < 4; ++ni) {
        const int n = n0 + wn * 64 + ni * 16 + lrow;
        char4 pk;
#pragma unroll
        for (int r = 0; r < 4; ++r) {
          float s = (float)acc[mi][ni][r] * d_act * d_wgt;
          s = fmaxf(s, 0.f);
          float xc = fminf(s / a2, 1.f);
          ((char*)&pk)[r] = (char)(int)rintf(xc * 15.f);
        }
        *(char4*)&Ct[(size_t)n * M + mb] = pk;
      }
    }
  } else {
    const float sc = (*s2p) * (1.f / 15.f) * (1.f / 127.f);
#pragma unroll
    for (int mi = 0; mi < 4; ++mi) {
      const int mb = m0 + wm * 64 + mi * 16 + qr;
#pragma unroll
      for (int ni = 0; ni < 4; ++ni) {
        const int n = n0 + wn * 64 + ni * 16 + lrow;
#pragma unroll
        for (int r = 0; r < 4; ++r)
          atomicAdd(&outp[(size_t)(mb + r) * N + n], (float)acc[mi][ni][r] * sc);
      }
    }
  }
}

template <bool RELUQ, bool AF32>
__global__ __launch_bounds__(256, 4) void gemm_i8_kernel(
    const void* __restrict__ Av, const char* __restrict__ B, void* __restrict__ Cv,
    float* __restrict__ outp,
    const int M, const int N, const int LDK, const int Kspan,
    const float* __restrict__ s0p, const float* __restrict__ s1p,
    const float* __restrict__ s2p) {
  gemm_body<RELUQ, AF32>(Av, B, Cv, outp, M, N, LDK, Kspan, blockIdx.z,
                         s0p, s1p, s2p);
}

// ---- fused GEMM1 (z=0, compute-bound) + adj f32->i8 quant (z=1, BW-bound) ----
__global__ __launch_bounds__(256, 4) void gemm1_adjq_kernel(
    const void* __restrict__ Av, const char* __restrict__ B, void* __restrict__ Cv,
    const float* __restrict__ s0p, const float* __restrict__ s1p,
    const float* __restrict__ s2p,
    const float* __restrict__ adj, char* __restrict__ adjq, long long an) {
  if (blockIdx.z == 1) {
    const long long bid = (long long)blockIdx.y * gridDim.x + blockIdx.x;  // 0..511
    for (long long i = (bid * 256 + threadIdx.x) * 16; i < an;
         i += (long long)512 * 256 * 16) {
      c16 r;
#pragma unroll
      for (int j = 0; j < 4; ++j) {
        float4 v = *(const float4*)&adj[i + 4 * j];
        r[4 * j + 0] = (char)(int)rintf(v.x * 127.f);
        r[4 * j + 1] = (char)(int)rintf(v.y * 127.f);
        r[4 * j + 2] = (char)(int)rintf(v.z * 127.f);
        r[4 * j + 3] = (char)(int)rintf(v.w * 127.f);
      }
      *(c16*)&adjq[i] = r;
    }
    return;
  }
  gemm_body<true, false>(Av, B, Cv, nullptr, 8192, 1024, 1024, 1024, 0,
                         s0p, s1p, s2p);
}

// ================= GEMM2: 256x256-tile 8-wave pipelined i8 GEMM =================
// C[8192,1024] += AdjQ[8192,8192] * StI[1024,8192]^T, split-K z=2 (Kspan 4096).
// 512 thr = 8 waves (wm=wv>>2 in 0..1 -> 128 M-rows; wn=wv&3 -> 64 N-cols).
// Triple-buffered 96KB LDS; depth-2 prefetch; boundary wait vmcnt(4) (counted,
// never drains in main loop); one raw s_barrier per K-tile; setprio around
// MFMA clusters. Same row format / swizzle / MFMA math as gemm_body.
__global__ __launch_bounds__(512, 2) void gemm2_8ph_kernel(
    const char* __restrict__ A, const char* __restrict__ B,
    float* __restrict__ outp, const float* __restrict__ s2p) {
  __shared__ __align__(16) char As[3][256 * 64];
  __shared__ __align__(16) char Bs[3][256 * 64];

  const int tid = threadIdx.x;
  const int lane = tid & 63;
  const int wv = tid >> 6;            // 0..7
  const int wm = wv >> 2, wn = wv & 3;
  const int m0 = blockIdx.x * 256, n0 = blockIdx.y * 256;
  const int kz = blockIdx.z * 4096;

  const int lrow = lane & 15;
  const int q16 = (((lane >> 4) + (lrow >> 1)) & 3) * 16;  // T2 read swizzle
  const int srow = tid >> 2;                                // 0..127
  const int scol = (((tid & 3) + 4 - ((tid >> 3) & 3)) & 3) * 16;  // src pre-swz
  const int wdst = wv * 1024;

  i32x4 acc[8][4];
#pragma unroll
  for (int i = 0; i < 8; ++i)
#pragma unroll
    for (int j = 0; j < 4; ++j) acc[i][j] = (i32x4){0, 0, 0, 0};

  auto stage = [&](int b, int kt) {
    const char* Ap = A + (size_t)(m0 + srow) * 8192 + kt + scol;
    gload_lds16(Ap, &As[b][wdst]);
    gload_lds16(Ap + (size_t)128 * 8192, &As[b][8192 + wdst]);
    const char* Bp = B + (size_t)(n0 + srow) * 8192 + kt + scol;
    gload_lds16(Bp, &Bs[b][wdst]);
    gload_lds16(Bp + (size_t)128 * 8192, &Bs[b][8192 + wdst]);
  };

  const int nt = 64;  // 4096 / 64
  stage(0, kz);
  stage(1, kz + 64);
  asm volatile("s_waitcnt vmcnt(4)" ::: "memory");  // tile0's 4 done
  __builtin_amdgcn_s_barrier();

  for (int t = 0; t < nt; ++t) {
    const int cur = t % 3;
    if (t + 2 < nt) stage((t + 2) % 3, kz + (t + 2) * 64);  // depth-2 prefetch

    i32x4 bf[4];
#pragma unroll
    for (int ni = 0; ni < 4; ++ni)
      bf[ni] = *(const i32x4*)&Bs[cur][(wn * 64 + ni * 16 + lrow) * 64 + q16];

#pragma unroll
    for (int g = 0; g < 4; ++g) {
      i32x4 a0 = *(const i32x4*)&As[cur][(wm * 128 + (2 * g) * 16 + lrow) * 64 + q16];
      i32x4 a1 = *(const i32x4*)&As[cur][(wm * 128 + (2 * g + 1) * 16 + lrow) * 64 + q16];
      __builtin_amdgcn_s_setprio(1);
#pragma unroll
      for (int ni = 0; ni < 4; ++ni) {
        acc[2 * g][ni] =
            __builtin_amdgcn_mfma_i32_16x16x64_i8(a0, bf[ni], acc[2 * g][ni], 0, 0, 0);
        acc[2 * g + 1][ni] =
            __builtin_amdgcn_mfma_i32_16x16x64_i8(a1, bf[ni], acc[2 * g + 1][ni], 0, 0, 0);
      }
      __builtin_amdgcn_s_setprio(0);
    }

    // counted boundary: allow the newest tile's 4 loads to stay in flight;
    // guarantees tile t+1's loads (issued at t-1) have landed in LDS.
    if (t + 2 < nt) {
      asm volatile("s_waitcnt vmcnt(4)" ::: "memory");
    } else {
      asm volatile("s_waitcnt vmcnt(0)" ::: "memory");
    }
    __builtin_amdgcn_s_barrier();
  }

  // epilogue: atomic f32 accumulate (split-K reduce), pre-zeroed out.
  const float sc = (*s2p) * (1.f / 15.f) * (1.f / 127.f);
  const int qr = (lane >> 4) * 4;
#pragma unroll
  for (int mi = 0; mi < 8; ++mi) {
    const int mb = m0 + wm * 128 + mi * 16 + qr;
#pragma unroll
    for (int ni = 0; ni < 4; ++ni) {
      const int n = n0 + wn * 64 + ni * 16 + lrow;
#pragma unroll
      for (int r = 0; r < 4; ++r)
        atomicAdd(&outp[(size_t)(mb + r) * 1024 + n], (float)acc[mi][ni][r] * sc);
    }
  }
}

extern "C" void kernel_launch(void* const* d_in, const int* in_sizes, int n_in,
                              void* d_out, int out_size, void* d_ws, size_t ws_size,
                              hipStream_t stream) {
  const float* input  = (const float*)d_in[0];   // 8192 x 1024
  const float* adj    = (const float*)d_in[1];   // 8192 x 8192
  // d_in[2] adj_scaling_factor = 2.0: pow2, cancels exactly in f32
  const float* weight = (const float*)d_in[3];   // 1024 x 1024
  const float* wgt_alpha  = (const float*)d_in[4];
  const float* act_alpha  = (const float*)d_in[5];
  const float* act_alpha2 = (const float*)d_in[6];
  float* out = (float*)d_out;                    // 8192 x 1024 f32

  constexpr int NN = 8192, INF = 1024, OUTF = 1024;
  constexpr size_t MB = 1024 * 1024;
  constexpr size_t HDR = 64 * 1024;

  char* ws = (char*)d_ws;
  double* stats = (double*)ws;                   // 16 B
  char* WtI  = ws + HDR;                         // OUTF x INF   (1 MB)
  char* XqI  = ws + HDR + 1 * MB;                // NN x INF     (8 MB)
  char* StI  = ws + HDR + 9 * MB;                // OUTF x NN    (8 MB)
  char* AdjQ = ws + HDR + 17 * MB;               // NN x NN      (64 MB)
  const size_t need = HDR + 81 * MB;

  hipMemsetAsync(stats, 0, 256, stream);
  hipMemsetAsync(out, 0, (size_t)NN * OUTF * sizeof(float), stream);  // atomic dst

  pre_kernel<<<256 + (NN * INF / 8) / 256, 256, 0, stream>>>(
      weight, stats, input, XqI, act_alpha, INF * OUTF, NN * INF);
  wquant_kernel<<<(INF * OUTF) / 256, 256, 0, stream>>>(weight, WtI, stats, wgt_alpha);

  if (ws_size >= need) {
    // GEMM1: Xq[8192x1024] @ Wt[1024x1024]^T -> Sq^T i8 [1024 x 8192], with
    // adjq (256 MB read / 64 MB write) riding the same dispatch on z=1.
    gemm1_adjq_kernel<<<dim3(NN / 128, OUTF / 128, 2), 256, 0, stream>>>(
        XqI, WtI, StI, act_alpha, wgt_alpha, act_alpha2, adj, AdjQ, (long long)NN * NN);
    // GEMM2: pipelined 256^2 kernel, split-K x2, atomic f32 reduce.
    gemm2_8ph_kernel<<<dim3(NN / 256, OUTF / 256, 2), 512, 0, stream>>>(
        AdjQ, StI, out, act_alpha2);
  } else {
    gemm_i8_kernel<true, false><<<dim3(NN / 128, OUTF / 128, 1), 256, 0, stream>>>(
        XqI, WtI, StI, nullptr, NN, OUTF, INF, INF,
        act_alpha, wgt_alpha, act_alpha2);
    gemm_i8_kernel<false, true><<<dim3(NN / 128, OUTF / 128, 2), 256, 0, stream>>>(
        adj, StI, nullptr, out, NN, OUTF, NN, NN / 2, nullptr, nullptr, act_alpha2);
  }
}

// Round 4
// 552.312 us; speedup vs baseline: 1.0116x; 1.0116x over previous
//
#include <hip/hip_runtime.h>

// GraphConvolution on MI355X (gfx950) — full-integer i8 pipeline.
//
// Algebra: Xq/act_delta = m in [0,15] (i8), Wq/wgt_delta in [-7,7] (i8),
// Sq/sup_delta = m2 in [0,15] (i8). Both matmuls are exact in i32. Only the
// adj->i8 quantization (scale 127) introduces error (~1 bf16-ULP of output).
//
// Time model (verified rounds 0-3): ~320us harness poison fills (fixed) +
// ~91us small passes & gemm1|adjq + GEMM2 ~140us. GEMM2 pipe floors: MFMA
// 35us, LDS 41us, HBM ~20us -> it runs 4x off floor = TLP/latency deficit.
//
// Round-7 (this round): GEMM2 back to the high-TLP regime, with better
// LDS economy:
//   - BM=128 x BN=256, 512 thr = 8 waves (2M x 4N), per-wave 64x64 out
//     -> LDS bytes/MFMA = 16384*(1/64+1/64) = 512 B (structural floor 41us;
//     round-0's 4-wave 128^2 was 768 B).
//   - Double-buffered 48 KB LDS -> 2 blocks/CU; grid (64,4,2) split-K x2 =
//     512 blocks -> 16 waves/CU = 4 waves/SIMD. m114: at this occupancy,
//     wave-level MFMA/VMEM overlap is implicit; no fine interleave needed.
//   - Sync structure = the VERIFIED round-2 2-phase __syncthreads body
//     (stage(next) issued before compute; one barrier per K-step).
//   - Round-3 lesson burned in: coarse phase-split + counted vmcnt at
//     1 block/CU (2 waves/SIMD) is NULL (m196's bad quadrant). Deleted.
//   - out-zeroing folded into pre_kernel (kills one fill dispatch).
//
// Round-5 learnings kept: no device-scope fences in hot kernels (round-4
// L2-writeback disaster); split-K reduce via f32 atomicAdd into pre-zeroed
// out (exact: |acc| < 2^24; commutative -> deterministic); pre fusion;
// gemm1|adjq z-fusion; T2 swizzle constants (0 bank conflicts measured).
//
// Grid congruence: linear mod 8 == bx mod 8 (64*y, 256*z ≡ 0 mod 8) ->
// all blocks sharing an A(adj)-strip land on one XCD/L2.

#define AS_G __attribute__((address_space(1)))
#define AS_L __attribute__((address_space(3)))

typedef int i32x4 __attribute__((ext_vector_type(4)));
typedef char c8 __attribute__((ext_vector_type(8)));
typedef char c16 __attribute__((ext_vector_type(16)));

static __device__ __forceinline__ void gload_lds16(const char* g, char* l) {
  __builtin_amdgcn_global_load_lds((const AS_G unsigned int*)g,
                                   (AS_L unsigned int*)l, 16, 0, 0);
}

// -- fused: wstats (blocks 0..255) | xquant (256..4351) | zero-out (4352..6399) --
__global__ void pre_kernel(const float* __restrict__ w, double* __restrict__ stats,
                           const float* __restrict__ x, char* __restrict__ xq,
                           const float* __restrict__ alpha_p,
                           float* __restrict__ outz, int wn, int xn) {
  if (blockIdx.x < 256) {
    double s = 0.0, ss = 0.0;
    for (int i = (blockIdx.x * 256 + threadIdx.x) * 4; i < wn; i += 256 * 256 * 4) {
      float4 v = *(const float4*)&w[i];
      s += (double)v.x + (double)v.y + (double)v.z + (double)v.w;
      ss += (double)v.x * v.x + (double)v.y * v.y + (double)v.z * v.z + (double)v.w * v.w;
    }
#pragma unroll
    for (int off = 32; off > 0; off >>= 1) {
      s  += __shfl_down(s, off);
      ss += __shfl_down(ss, off);
    }
    if ((threadIdx.x & 63) == 0) {
      atomicAdd(&stats[0], s);
      atomicAdd(&stats[1], ss);
    }
  } else if (blockIdx.x < 256 + 4096) {
    int i = ((blockIdx.x - 256) * 256 + threadIdx.x) * 8;
    if (i >= xn) return;
    const float alpha = *alpha_p;
    float4 v0 = *(const float4*)&x[i];
    float4 v1 = *(const float4*)&x[i + 4];
    c8 o;
    o[0] = (char)(int)rintf(fminf(v0.x / alpha, 1.f) * 15.f);
    o[1] = (char)(int)rintf(fminf(v0.y / alpha, 1.f) * 15.f);
    o[2] = (char)(int)rintf(fminf(v0.z / alpha, 1.f) * 15.f);
    o[3] = (char)(int)rintf(fminf(v0.w / alpha, 1.f) * 15.f);
    o[4] = (char)(int)rintf(fminf(v1.x / alpha, 1.f) * 15.f);
    o[5] = (char)(int)rintf(fminf(v1.y / alpha, 1.f) * 15.f);
    o[6] = (char)(int)rintf(fminf(v1.z / alpha, 1.f) * 15.f);
    o[7] = (char)(int)rintf(fminf(v1.w / alpha, 1.f) * 15.f);
    *(c8*)&xq[i] = o;
  } else {
    // zero the atomic-reduce destination: 8192x1024 f32, 16 floats/thread
    const size_t i = ((size_t)(blockIdx.x - 4352) * 256 + threadIdx.x) * 16;
    const float4 z = {0.f, 0.f, 0.f, 0.f};
    *(float4*)&outz[i]      = z;
    *(float4*)&outz[i + 4]  = z;
    *(float4*)&outz[i + 8]  = z;
    *(float4*)&outz[i + 12] = z;
  }
}

// ------------- weight quant -> i8 levels, transposed (OUTF x INF) -------------
__global__ void wquant_kernel(const float* __restrict__ w, char* __restrict__ wt,
                              const double* __restrict__ stats,
                              const float* __restrict__ alpha_p) {
  int idx = blockIdx.x * 256 + threadIdx.x;
  const double cnt = 1048576.0;
  const double mean = stats[0] / cnt;
  const double var = (stats[1] - stats[0] * mean) / (cnt - 1.0);  // ddof=1
  const float meanf = (float)mean;
  const float stdf = (float)sqrt(var);
  const float alpha = *alpha_p;
  const int n = idx >> 10;          // out-feature
  const int k = idx & 1023;         // in-feature
  float wn = (w[(size_t)k * 1024 + n] - meanf) / stdf;
  float wc = fminf(fmaxf(wn / alpha, -1.f), 1.f);
  wt[idx] = (char)(int)copysignf(rintf(fabsf(wc) * 7.f), wc);  // -7..7
}

// ---------------- 2-phase i8 GEMM body (GEMM1 + AF32 fallback) ----------------
// RELUQ: epilogue scale*relu*quant -> i8, store transposed Ct[N][M].
// else : split-K: epilogue atomicAdd((float)acc * sc) into pre-zeroed f32 out.
// T2 swizzle: LDS(row, c) holds Global(row, (c - (row>>1))&3).
template <bool RELUQ, bool AF32>
static __device__ __forceinline__ void gemm_body(
    const void* __restrict__ Av, const char* __restrict__ B, void* __restrict__ Cv,
    float* __restrict__ outp,
    const int M, const int N, const int LDK, const int Kspan, const int zidx,
    const float* s0p, const float* s1p, const float* s2p) {
  __shared__ __align__(16) char As[2][128 * 64];
  __shared__ __align__(16) char Bs[2][128 * 64];

  const int tid = threadIdx.x;
  const int lane = tid & 63;
  const int wv = tid >> 6;
  const int wm = wv >> 1, wn = wv & 1;
  const int m0 = blockIdx.x * 128, n0 = blockIdx.y * 128;
  const int kz = zidx * Kspan;

  const int srow = tid >> 2;
  const int scol = (((tid & 3) + 4 - ((tid >> 3) & 3)) & 3) * 16;
  const int frow = tid >> 1;
  const int ft = (tid & 1) * 2;
  const int fsh = (tid >> 2) & 3;

  i32x4 acc[4][4];
#pragma unroll
  for (int i = 0; i < 4; ++i)
#pragma unroll
    for (int j = 0; j < 4; ++j) acc[i][j] = (i32x4){0, 0, 0, 0};

  const int lrow = lane & 15;
  const int q16 = (((lane >> 4) + (lrow >> 1)) & 3) * 16;

  auto stage = [&](int b, int kt) {
    if (AF32) {
      const float* Af = (const float*)Av;
      const float* src = Af + (size_t)(m0 + frow) * LDK + kt + (tid & 1) * 32;
      c16 p0, p1;
#pragma unroll
      for (int j = 0; j < 4; ++j) {
        float4 v = *(const float4*)(src + 4 * j);
        p0[4 * j + 0] = (char)(int)rintf(v.x * 127.f);
        p0[4 * j + 1] = (char)(int)rintf(v.y * 127.f);
        p0[4 * j + 2] = (char)(int)rintf(v.z * 127.f);
        p0[4 * j + 3] = (char)(int)rintf(v.w * 127.f);
      }
#pragma unroll
      for (int j = 0; j < 4; ++j) {
        float4 v = *(const float4*)(src + 16 + 4 * j);
        p1[4 * j + 0] = (char)(int)rintf(v.x * 127.f);
        p1[4 * j + 1] = (char)(int)rintf(v.y * 127.f);
        p1[4 * j + 2] = (char)(int)rintf(v.z * 127.f);
        p1[4 * j + 3] = (char)(int)rintf(v.w * 127.f);
      }
      *(c16*)&As[b][frow * 64 + (((ft + 0) + fsh) & 3) * 16] = p0;
      *(c16*)&As[b][frow * 64 + (((ft + 1) + fsh) & 3) * 16] = p1;
    } else {
      const char* Ab = (const char*)Av;
      gload_lds16(Ab + (size_t)(m0 + srow) * LDK + kt + scol, &As[b][wv * 1024]);
      gload_lds16(Ab + (size_t)(m0 + 64 + srow) * LDK + kt + scol,
                  &As[b][4096 + wv * 1024]);
    }
    gload_lds16(B + (size_t)(n0 + srow) * LDK + kt + scol, &Bs[b][wv * 1024]);
    gload_lds16(B + (size_t)(n0 + 64 + srow) * LDK + kt + scol,
                &Bs[b][4096 + wv * 1024]);
  };

  const int nt = Kspan / 64;
  stage(0, kz);
  __syncthreads();

  for (int t = 0; t < nt; ++t) {
    const int cur = t & 1;
    if (t + 1 < nt) stage(cur ^ 1, kz + (t + 1) * 64);

    i32x4 af[4], bfr[4];
#pragma unroll
    for (int mi = 0; mi < 4; ++mi)
      af[mi] = *(const i32x4*)&As[cur][(wm * 64 + mi * 16 + lrow) * 64 + q16];
#pragma unroll
    for (int ni = 0; ni < 4; ++ni)
      bfr[ni] = *(const i32x4*)&Bs[cur][(wn * 64 + ni * 16 + lrow) * 64 + q16];
#pragma unroll
    for (int mi = 0; mi < 4; ++mi)
#pragma unroll
      for (int ni = 0; ni < 4; ++ni)
        acc[mi][ni] =
            __builtin_amdgcn_mfma_i32_16x16x64_i8(af[mi], bfr[ni], acc[mi][ni], 0, 0, 0);

    __syncthreads();
  }

  const int qr = (lane >> 4) * 4;
  if (RELUQ) {
    const float d_act = *s0p / 15.f;
    const float d_wgt = *s1p / 7.f;
    const float a2 = *s2p;
    char* Ct = (char*)Cv;  // N x M i8
#pragma unroll
    for (int mi = 0; mi < 4; ++mi) {
      const int mb = m0 + wm * 64 + mi * 16 + qr;
#pragma unroll
      for (int ni = 0; ni < 4; ++ni) {
        const int n = n0 + wn * 64 + ni * 16 + lrow;
        char4 pk;
#pragma unroll
        for (int r = 0; r < 4; ++r) {
          float s = (float)acc[mi][ni][r] * d_act * d_wgt;
          s = fmaxf(s, 0.f);
          float xc = fminf(s / a2, 1.f);
          ((char*)&pk)[r] = (char)(int)rintf(xc * 15.f);
        }
        *(char4*)&Ct[(size_t)n * M + mb] = pk;
      }
    }
  } else {
    const float sc = (*s2p) * (1.f / 15.f) * (1.f / 127.f);
#pragma unroll
    for (int mi = 0; mi < 4; ++mi) {
      const int mb = m0 + wm * 64 + mi * 16 + qr;
#pragma unroll
      for (int ni = 0; ni < 4; ++ni) {
        const int n = n0 + wn * 64 + ni * 16 + lrow;
#pragma unroll
        for (int r = 0; r < 4; ++r)
          atomicAdd(&outp[(size_t)(mb + r) * N + n], (float)acc[mi][ni][r] * sc);
      }
    }
  }
}

template <bool RELUQ, bool AF32>
__global__ __launch_bounds__(256, 4) void gemm_i8_kernel(
    const void* __restrict__ Av, const char* __restrict__ B, void* __restrict__ Cv,
    float* __restrict__ outp,
    const int M, const int N, const int LDK, const int Kspan,
    const float* __restrict__ s0p, const float* __restrict__ s1p,
    const float* __restrict__ s2p) {
  gemm_body<RELUQ, AF32>(Av, B, Cv, outp, M, N, LDK, Kspan, blockIdx.z,
                         s0p, s1p, s2p);
}

// ---- fused GEMM1 (z=0, compute-bound) + adj f32->i8 quant (z=1, BW-bound) ----
__global__ __launch_bounds__(256, 4) void gemm1_adjq_kernel(
    const void* __restrict__ Av, const char* __restrict__ B, void* __restrict__ Cv,
    const float* __restrict__ s0p, const float* __restrict__ s1p,
    const float* __restrict__ s2p,
    const float* __restrict__ adj, char* __restrict__ adjq, long long an) {
  if (blockIdx.z == 1) {
    const long long bid = (long long)blockIdx.y * gridDim.x + blockIdx.x;  // 0..511
    for (long long i = (bid * 256 + threadIdx.x) * 16; i < an;
         i += (long long)512 * 256 * 16) {
      c16 r;
#pragma unroll
      for (int j = 0; j < 4; ++j) {
        float4 v = *(const float4*)&adj[i + 4 * j];
        r[4 * j + 0] = (char)(int)rintf(v.x * 127.f);
        r[4 * j + 1] = (char)(int)rintf(v.y * 127.f);
        r[4 * j + 2] = (char)(int)rintf(v.z * 127.f);
        r[4 * j + 3] = (char)(int)rintf(v.w * 127.f);
      }
      *(c16*)&adjq[i] = r;
    }
    return;
  }
  gemm_body<true, false>(Av, B, Cv, nullptr, 8192, 1024, 1024, 1024, 0,
                         s0p, s1p, s2p);
}

// ============ GEMM2: 128x256-tile, 8-wave, 2 blocks/CU, split-K x2 ============
// out[8192,1024] += AdjQ[8192,8192] * StI[1024,8192]^T * sc, Kspan 4096/z.
// 512 thr = 8 waves (wm=wv>>2 -> 2 M-halves of 64; wn=wv&3 -> 4 N-quads of 64).
// Per-wave 64x64 out -> acc[4][4] (identical shape to verified gemm_body).
// LDS 2x(8+16) KB = 48 KB -> 2 blocks/CU -> 4 waves/SIMD (TLP regime, m114).
// Same T2 swizzle / staging map / 2-phase __syncthreads loop as gemm_body.
__global__ __launch_bounds__(512, 4) void gemm2_kernel(
    const char* __restrict__ A, const char* __restrict__ B,
    float* __restrict__ outp, const float* __restrict__ s2p) {
  __shared__ __align__(16) char As[2][128 * 64];
  __shared__ __align__(16) char Bs[2][256 * 64];

  const int tid = threadIdx.x;
  const int lane = tid & 63;
  const int wv = tid >> 6;            // 0..7
  const int wm = wv >> 2, wn = wv & 3;
  const int m0 = blockIdx.x * 128, n0 = blockIdx.y * 256;
  const int kz = blockIdx.z * 4096;

  const int lrow = lane & 15;
  const int q16 = (((lane >> 4) + (lrow >> 1)) & 3) * 16;          // T2 read swz
  const int srow = tid >> 2;                                        // 0..127
  const int scol = (((tid & 3) + 4 - ((tid >> 3) & 3)) & 3) * 16;   // src pre-swz

  i32x4 acc[4][4];
#pragma unroll
  for (int i = 0; i < 4; ++i)
#pragma unroll
    for (int j = 0; j < 4; ++j) acc[i][j] = (i32x4){0, 0, 0, 0};

  auto stage = [&](int b, int kt) {
    // A: 128 rows x 64 B = 8 KB, one gload round (512 thr x 16 B).
    gload_lds16(A + (size_t)(m0 + srow) * 8192 + kt + scol, &As[b][wv * 1024]);
    // B: 256 rows = two rounds; (row+128)>>1 & 3 == row>>1 & 3, so same scol.
    const char* Bp = B + (size_t)(n0 + srow) * 8192 + kt + scol;
    gload_lds16(Bp, &Bs[b][wv * 1024]);
    gload_lds16(Bp + (size_t)128 * 8192, &Bs[b][8192 + wv * 1024]);
  };

  const int nt = 64;  // 4096 / 64
  stage(0, kz);
  __syncthreads();

  for (int t = 0; t < nt; ++t) {
    const int cur = t & 1;
    if (t + 1 < nt) stage(cur ^ 1, kz + (t + 1) * 64);  // in flight during compute

    i32x4 af[4], bfr[4];
#pragma unroll
    for (int mi = 0; mi < 4; ++mi)
      af[mi] = *(const i32x4*)&As[cur][(wm * 64 + mi * 16 + lrow) * 64 + q16];
#pragma unroll
    for (int ni = 0; ni < 4; ++ni)
      bfr[ni] = *(const i32x4*)&Bs[cur][(wn * 64 + ni * 16 + lrow) * 64 + q16];
#pragma unroll
    for (int mi = 0; mi < 4; ++mi)
#pragma unroll
      for (int ni = 0; ni < 4; ++ni)
        acc[mi][ni] =
            __builtin_amdgcn_mfma_i32_16x16x64_i8(af[mi], bfr[ni], acc[mi][ni], 0, 0, 0);

    __syncthreads();  // drains next-tile stage (vmcnt) + this tile's reads (lgkm)
  }

  // split-K reduce: atomic f32 accumulate into pre-zeroed out. No fences.
  const float sc = (*s2p) * (1.f / 15.f) * (1.f / 127.f);
  const int qr = (lane >> 4) * 4;
#pragma unroll
  for (int mi = 0; mi < 4; ++mi) {
    const int mb = m0 + wm * 64 + mi * 16 + qr;
#pragma unroll
    for (int ni = 0; ni < 4; ++ni) {
      const int n = n0 + wn * 64 + ni * 16 + lrow;
#pragma unroll
      for (int r = 0; r < 4; ++r)
        atomicAdd(&outp[(size_t)(mb + r) * 1024 + n], (float)acc[mi][ni][r] * sc);
    }
  }
}

extern "C" void kernel_launch(void* const* d_in, const int* in_sizes, int n_in,
                              void* d_out, int out_size, void* d_ws, size_t ws_size,
                              hipStream_t stream) {
  const float* input  = (const float*)d_in[0];   // 8192 x 1024
  const float* adj    = (const float*)d_in[1];   // 8192 x 8192
  // d_in[2] adj_scaling_factor = 2.0: pow2, cancels exactly in f32
  const float* weight = (const float*)d_in[3];   // 1024 x 1024
  const float* wgt_alpha  = (const float*)d_in[4];
  const float* act_alpha  = (const float*)d_in[5];
  const float* act_alpha2 = (const float*)d_in[6];
  float* out = (float*)d_out;                    // 8192 x 1024 f32

  constexpr int NN = 8192, INF = 1024, OUTF = 1024;
  constexpr size_t MB = 1024 * 1024;
  constexpr size_t HDR = 64 * 1024;

  char* ws = (char*)d_ws;
  double* stats = (double*)ws;                   // 16 B
  char* WtI  = ws + HDR;                         // OUTF x INF   (1 MB)
  char* XqI  = ws + HDR + 1 * MB;                // NN x INF     (8 MB)
  char* StI  = ws + HDR + 9 * MB;                // OUTF x NN    (8 MB)
  char* AdjQ = ws + HDR + 17 * MB;               // NN x NN      (64 MB)
  const size_t need = HDR + 81 * MB;

  hipMemsetAsync(stats, 0, 256, stream);

  // pre: wstats | xquant | out-zero (atomic-reduce destination)
  pre_kernel<<<256 + 4096 + 2048, 256, 0, stream>>>(
      weight, stats, input, XqI, act_alpha, out, INF * OUTF, NN * INF);
  wquant_kernel<<<(INF * OUTF) / 256, 256, 0, stream>>>(weight, WtI, stats, wgt_alpha);

  if (ws_size >= need) {
    // GEMM1: Xq[8192x1024] @ Wt[1024x1024]^T -> Sq^T i8 [1024 x 8192], with
    // adjq (256 MB read / 64 MB write) riding the same dispatch on z=1.
    gemm1_adjq_kernel<<<dim3(NN / 128, OUTF / 128, 2), 256, 0, stream>>>(
        XqI, WtI, StI, act_alpha, wgt_alpha, act_alpha2, adj, AdjQ, (long long)NN * NN);
    // GEMM2: 128x256-tile 8-wave, 2 blocks/CU, split-K x2, atomic f32 reduce.
    gemm2_kernel<<<dim3(NN / 128, OUTF / 256, 2), 512, 0, stream>>>(
        AdjQ, StI, out, act_alpha2);
  } else {
    gemm_i8_kernel<true, false><<<dim3(NN / 128, OUTF / 128, 1), 256, 0, stream>>>(
        XqI, WtI, StI, nullptr, NN, OUTF, INF, INF,
        act_alpha, wgt_alpha, act_alpha2);
    gemm_i8_kernel<false, true><<<dim3(NN / 128, OUTF / 128, 2), 256, 0, stream>>>(
        adj, StI, nullptr, out, NN, OUTF, NN, NN / 2, nullptr, nullptr, act_alpha2);
  }
}

// Round 5
// 540.206 us; speedup vs baseline: 1.0343x; 1.0224x over previous
//
#include <hip/hip_runtime.h>

// GraphConvolution on MI355X (gfx950) — full-integer i8 pipeline.
//
// Algebra: Xq/act_delta = m in [0,15] (i8), Wq/wgt_delta in [-7,7] (i8),
// Sq/sup_delta = m2 in [0,15] (i8). Both matmuls are exact in i32. Only the
// adj->i8 quantization (scale 127) introduces error (~1 bf16-ULP of output).
//
// Time model (rounds 0-4): ~320us harness poison fills (fixed) + pre/wquant
// ~13us + gemm1|adjq ~70us + GEMM2 ~140us. GEMM2 pinned at 25% of the
// 3944-TOPS i8 ceiling across THREE 2-phase geometries (128^2 4blk/CU,
// 256^2 coarse-vmcnt 1blk/CU, 128x256 2blk/CU) -> the ~700cy/step residue
// is the barrier-drain tax (m233), only removable by the fine interleave.
//
// Round-8 (this round): faithful m201-class port for GEMM2 (round-3 was the
// coarse strawman m196 warns about):
//   - 256x256 tile, 512 thr, 8 waves (2Mx4N, per-wave 128x64), split-K x2,
//     grid (32,4,2) = 256 blocks = 1/CU; TRIPLE-buffered 96 KB LDS.
//   - 2 fine phases per K-tile: {ds_read quadrant || issue 2 gload_lds of
//     tile t+2} -> BAR -> setprio(1) 16-MFMA setprio(0) -> BAR.
//   - Counted vmcnt(4) once per K-tile, at the END of P1 (before the barrier
//     preceding the next tile's first reads) = m201's phase-4/8 placement.
//     Never drains to 0 in the main loop. Per-wave staging counts are
//     uniform, so per-wave vmcnt + barrier => all slices landed.
//   - All barriers/waits are asm volatile with "memory" clobber so plain
//     LDS reads can't hoist across them; compiler handles lgkmcnt deps.
//   - Staging/frag/acc/epilogue maps = round-3's harness-verified maps.
// GEMM1 stays on the verified 2-phase body (its dispatch is adjq-BW-bound).
//
// Kept learnings: no device-scope fences in hot kernels (round-1 L2-flush
// disaster); split-K reduce via f32 atomicAdd into pre-zeroed out (exact:
// |acc| < 2^24, commutative); pre(wstats|xquant|out-zero) fusion;
// gemm1|adjq z-fusion; T2 LDS swizzle (0 bank conflicts measured).
//
// Grid congruence: linear mod 8 == bx mod 8 (32*y, 128*z ≡ 0 mod 8) ->
// all blocks sharing an adj strip land on one XCD/L2.

#define AS_G __attribute__((address_space(1)))
#define AS_L __attribute__((address_space(3)))

typedef int i32x4 __attribute__((ext_vector_type(4)));
typedef char c8 __attribute__((ext_vector_type(8)));
typedef char c16 __attribute__((ext_vector_type(16)));

static __device__ __forceinline__ void gload_lds16(const char* g, char* l) {
  __builtin_amdgcn_global_load_lds((const AS_G unsigned int*)g,
                                   (AS_L unsigned int*)l, 16, 0, 0);
}

// -- fused: wstats (blocks 0..255) | xquant (256..4351) | zero-out (4352..6399) --
__global__ void pre_kernel(const float* __restrict__ w, double* __restrict__ stats,
                           const float* __restrict__ x, char* __restrict__ xq,
                           const float* __restrict__ alpha_p,
                           float* __restrict__ outz, int wn, int xn) {
  if (blockIdx.x < 256) {
    double s = 0.0, ss = 0.0;
    for (int i = (blockIdx.x * 256 + threadIdx.x) * 4; i < wn; i += 256 * 256 * 4) {
      float4 v = *(const float4*)&w[i];
      s += (double)v.x + (double)v.y + (double)v.z + (double)v.w;
      ss += (double)v.x * v.x + (double)v.y * v.y + (double)v.z * v.z + (double)v.w * v.w;
    }
#pragma unroll
    for (int off = 32; off > 0; off >>= 1) {
      s  += __shfl_down(s, off);
      ss += __shfl_down(ss, off);
    }
    if ((threadIdx.x & 63) == 0) {
      atomicAdd(&stats[0], s);
      atomicAdd(&stats[1], ss);
    }
  } else if (blockIdx.x < 256 + 4096) {
    int i = ((blockIdx.x - 256) * 256 + threadIdx.x) * 8;
    if (i >= xn) return;
    const float alpha = *alpha_p;
    float4 v0 = *(const float4*)&x[i];
    float4 v1 = *(const float4*)&x[i + 4];
    c8 o;
    o[0] = (char)(int)rintf(fminf(v0.x / alpha, 1.f) * 15.f);
    o[1] = (char)(int)rintf(fminf(v0.y / alpha, 1.f) * 15.f);
    o[2] = (char)(int)rintf(fminf(v0.z / alpha, 1.f) * 15.f);
    o[3] = (char)(int)rintf(fminf(v0.w / alpha, 1.f) * 15.f);
    o[4] = (char)(int)rintf(fminf(v1.x / alpha, 1.f) * 15.f);
    o[5] = (char)(int)rintf(fminf(v1.y / alpha, 1.f) * 15.f);
    o[6] = (char)(int)rintf(fminf(v1.z / alpha, 1.f) * 15.f);
    o[7] = (char)(int)rintf(fminf(v1.w / alpha, 1.f) * 15.f);
    *(c8*)&xq[i] = o;
  } else {
    // zero the atomic-reduce destination: 8192x1024 f32, 16 floats/thread
    const size_t i = ((size_t)(blockIdx.x - 4352) * 256 + threadIdx.x) * 16;
    const float4 z = {0.f, 0.f, 0.f, 0.f};
    *(float4*)&outz[i]      = z;
    *(float4*)&outz[i + 4]  = z;
    *(float4*)&outz[i + 8]  = z;
    *(float4*)&outz[i + 12] = z;
  }
}

// ------------- weight quant -> i8 levels, transposed (OUTF x INF) -------------
__global__ void wquant_kernel(const float* __restrict__ w, char* __restrict__ wt,
                              const double* __restrict__ stats,
                              const float* __restrict__ alpha_p) {
  int idx = blockIdx.x * 256 + threadIdx.x;
  const double cnt = 1048576.0;
  const double mean = stats[0] / cnt;
  const double var = (stats[1] - stats[0] * mean) / (cnt - 1.0);  // ddof=1
  const float meanf = (float)mean;
  const float stdf = (float)sqrt(var);
  const float alpha = *alpha_p;
  const int n = idx >> 10;          // out-feature
  const int k = idx & 1023;         // in-feature
  float wn = (w[(size_t)k * 1024 + n] - meanf) / stdf;
  float wc = fminf(fmaxf(wn / alpha, -1.f), 1.f);
  wt[idx] = (char)(int)copysignf(rintf(fabsf(wc) * 7.f), wc);  // -7..7
}

// ---------------- 2-phase i8 GEMM body (GEMM1 + AF32 fallback) ----------------
// RELUQ: epilogue scale*relu*quant -> i8, store transposed Ct[N][M].
// else : split-K: epilogue atomicAdd((float)acc * sc) into pre-zeroed f32 out.
// T2 swizzle: LDS(row, c) holds Global(row, (c - (row>>1))&3).
template <bool RELUQ, bool AF32>
static __device__ __forceinline__ void gemm_body(
    const void* __restrict__ Av, const char* __restrict__ B, void* __restrict__ Cv,
    float* __restrict__ outp,
    const int M, const int N, const int LDK, const int Kspan, const int zidx,
    const float* s0p, const float* s1p, const float* s2p) {
  __shared__ __align__(16) char As[2][128 * 64];
  __shared__ __align__(16) char Bs[2][128 * 64];

  const int tid = threadIdx.x;
  const int lane = tid & 63;
  const int wv = tid >> 6;
  const int wm = wv >> 1, wn = wv & 1;
  const int m0 = blockIdx.x * 128, n0 = blockIdx.y * 128;
  const int kz = zidx * Kspan;

  const int srow = tid >> 2;
  const int scol = (((tid & 3) + 4 - ((tid >> 3) & 3)) & 3) * 16;
  const int frow = tid >> 1;
  const int ft = (tid & 1) * 2;
  const int fsh = (tid >> 2) & 3;

  i32x4 acc[4][4];
#pragma unroll
  for (int i = 0; i < 4; ++i)
#pragma unroll
    for (int j = 0; j < 4; ++j) acc[i][j] = (i32x4){0, 0, 0, 0};

  const int lrow = lane & 15;
  const int q16 = (((lane >> 4) + (lrow >> 1)) & 3) * 16;

  auto stage = [&](int b, int kt) {
    if (AF32) {
      const float* Af = (const float*)Av;
      const float* src = Af + (size_t)(m0 + frow) * LDK + kt + (tid & 1) * 32;
      c16 p0, p1;
#pragma unroll
      for (int j = 0; j < 4; ++j) {
        float4 v = *(const float4*)(src + 4 * j);
        p0[4 * j + 0] = (char)(int)rintf(v.x * 127.f);
        p0[4 * j + 1] = (char)(int)rintf(v.y * 127.f);
        p0[4 * j + 2] = (char)(int)rintf(v.z * 127.f);
        p0[4 * j + 3] = (char)(int)rintf(v.w * 127.f);
      }
#pragma unroll
      for (int j = 0; j < 4; ++j) {
        float4 v = *(const float4*)(src + 16 + 4 * j);
        p1[4 * j + 0] = (char)(int)rintf(v.x * 127.f);
        p1[4 * j + 1] = (char)(int)rintf(v.y * 127.f);
        p1[4 * j + 2] = (char)(int)rintf(v.z * 127.f);
        p1[4 * j + 3] = (char)(int)rintf(v.w * 127.f);
      }
      *(c16*)&As[b][frow * 64 + (((ft + 0) + fsh) & 3) * 16] = p0;
      *(c16*)&As[b][frow * 64 + (((ft + 1) + fsh) & 3) * 16] = p1;
    } else {
      const char* Ab = (const char*)Av;
      gload_lds16(Ab + (size_t)(m0 + srow) * LDK + kt + scol, &As[b][wv * 1024]);
      gload_lds16(Ab + (size_t)(m0 + 64 + srow) * LDK + kt + scol,
                  &As[b][4096 + wv * 1024]);
    }
    gload_lds16(B + (size_t)(n0 + srow) * LDK + kt + scol, &Bs[b][wv * 1024]);
    gload_lds16(B + (size_t)(n0 + 64 + srow) * LDK + kt + scol,
                &Bs[b][4096 + wv * 1024]);
  };

  const int nt = Kspan / 64;
  stage(0, kz);
  __syncthreads();

  for (int t = 0; t < nt; ++t) {
    const int cur = t & 1;
    if (t + 1 < nt) stage(cur ^ 1, kz + (t + 1) * 64);

    i32x4 af[4], bfr[4];
#pragma unroll
    for (int mi = 0; mi < 4; ++mi)
      af[mi] = *(const i32x4*)&As[cur][(wm * 64 + mi * 16 + lrow) * 64 + q16];
#pragma unroll
    for (int ni = 0; ni < 4; ++ni)
      bfr[ni] = *(const i32x4*)&Bs[cur][(wn * 64 + ni * 16 + lrow) * 64 + q16];
#pragma unroll
    for (int mi = 0; mi < 4; ++mi)
#pragma unroll
      for (int ni = 0; ni < 4; ++ni)
        acc[mi][ni] =
            __builtin_amdgcn_mfma_i32_16x16x64_i8(af[mi], bfr[ni], acc[mi][ni], 0, 0, 0);

    __syncthreads();
  }

  const int qr = (lane >> 4) * 4;
  if (RELUQ) {
    const float d_act = *s0p / 15.f;
    const float d_wgt = *s1p / 7.f;
    const float a2 = *s2p;
    char* Ct = (char*)Cv;  // N x M i8
#pragma unroll
    for (int mi = 0; mi < 4; ++mi) {
      const int mb = m0 + wm * 64 + mi * 16 + qr;
#pragma unroll
      for (int ni = 0; ni < 4; ++ni) {
        const int n = n0 + wn * 64 + ni * 16 + lrow;
        char4 pk;
#pragma unroll
        for (int r = 0; r < 4; ++r) {
          float s = (float)acc[mi][ni][r] * d_act * d_wgt;
          s = fmaxf(s, 0.f);
          float xc = fminf(s / a2, 1.f);
          ((char*)&pk)[r] = (char)(int)rintf(xc * 15.f);
        }
        *(char4*)&Ct[(size_t)n * M + mb] = pk;
      }
    }
  } else {
    const float sc = (*s2p) * (1.f / 15.f) * (1.f / 127.f);
#pragma unroll
    for (int mi = 0; mi < 4; ++mi) {
      const int mb = m0 + wm * 64 + mi * 16 + qr;
#pragma unroll
      for (int ni = 0; ni < 4; ++ni) {
        const int n = n0 + wn * 64 + ni * 16 + lrow;
#pragma unroll
        for (int r = 0; r < 4; ++r)
          atomicAdd(&outp[(size_t)(mb + r) * N + n], (float)acc[mi][ni][r] * sc);
      }
    }
  }
}

template <bool RELUQ, bool AF32>
__global__ __launch_bounds__(256, 4) void gemm_i8_kernel(
    const void* __restrict__ Av, const char* __restrict__ B, void* __restrict__ Cv,
    float* __restrict__ outp,
    const int M, const int N, const int LDK, const int Kspan,
    const float* __restrict__ s0p, const float* __restrict__ s1p,
    const float* __restrict__ s2p) {
  gemm_body<RELUQ, AF32>(Av, B, Cv, outp, M, N, LDK, Kspan, blockIdx.z,
                         s0p, s1p, s2p);
}

// ---- fused GEMM1 (z=0, compute-bound) + adj f32->i8 quant (z=1, BW-bound) ----
__global__ __launch_bounds__(256, 4) void gemm1_adjq_kernel(
    const void* __restrict__ Av, const char* __restrict__ B, void* __restrict__ Cv,
    const float* __restrict__ s0p, const float* __restrict__ s1p,
    const float* __restrict__ s2p,
    const float* __restrict__ adj, char* __restrict__ adjq, long long an) {
  if (blockIdx.z == 1) {
    const long long bid = (long long)blockIdx.y * gridDim.x + blockIdx.x;  // 0..511
    for (long long i = (bid * 256 + threadIdx.x) * 16; i < an;
         i += (long long)512 * 256 * 16) {
      c16 r;
#pragma unroll
      for (int j = 0; j < 4; ++j) {
        float4 v = *(const float4*)&adj[i + 4 * j];
        r[4 * j + 0] = (char)(int)rintf(v.x * 127.f);
        r[4 * j + 1] = (char)(int)rintf(v.y * 127.f);
        r[4 * j + 2] = (char)(int)rintf(v.z * 127.f);
        r[4 * j + 3] = (char)(int)rintf(v.w * 127.f);
      }
      *(c16*)&adjq[i] = r;
    }
    return;
  }
  gemm_body<true, false>(Av, B, Cv, nullptr, 8192, 1024, 1024, 1024, 0,
                         s0p, s1p, s2p);
}

// ====== GEMM2: 256x256-tile, 8-wave, fine-interleaved pipeline (m201-class) =====
// out[8192,1024] += AdjQ[8192,8192] * StI[1024,8192]^T * sc, split-K x2.
// 512 thr = 8 waves; wm=wv>>2 (128-row half), wn=wv&3 (64-col quad); per-wave
// 128x64 out = acc[8][4]. Triple-buffered 96 KB LDS, depth-2 prefetch.
// Per K-tile: 2 phases, each {ds_read quadrant || 2 gload_lds of tile t+2}
// -> BAR -> setprio(1) 16-MFMA setprio(0) -> BAR. vmcnt(4) ONCE per K-tile,
// at end of P1, validating tile t+1 before its first reads (m201 placement).
// Per-wave staging counts uniform => per-wave vmcnt + barrier covers all
// waves' slices. Staging/frag/acc maps = round-3's harness-verified maps.
__global__ __launch_bounds__(512, 2) void gemm2_pipe_kernel(
    const char* __restrict__ A, const char* __restrict__ B,
    float* __restrict__ outp, const float* __restrict__ s2p) {
  __shared__ __align__(16) char As[3][256 * 64];
  __shared__ __align__(16) char Bs[3][256 * 64];

  const int tid = threadIdx.x;
  const int lane = tid & 63;
  const int wv = tid >> 6;            // 0..7
  const int wm = wv >> 2, wn = wv & 3;
  const int m0 = blockIdx.x * 256, n0 = blockIdx.y * 256;
  const int kz = blockIdx.z * 4096;

  const int lrow = lane & 15;
  const int q16 = (((lane >> 4) + (lrow >> 1)) & 3) * 16;          // T2 read swz
  const int srow = tid >> 2;                                        // 0..127
  const int scol = (((tid & 3) + 4 - ((tid >> 3) & 3)) & 3) * 16;   // src pre-swz
  const int wdst = wv * 1024;

  i32x4 acc[8][4];
#pragma unroll
  for (int i = 0; i < 8; ++i)
#pragma unroll
    for (int j = 0; j < 4; ++j) acc[i][j] = (i32x4){0, 0, 0, 0};

  auto stageA = [&](int b, int kt) {  // 2 gload instrs: A rows 0..127, 128..255
    const char* Ap = A + (size_t)(m0 + srow) * 8192 + kt + scol;
    gload_lds16(Ap, &As[b][wdst]);
    gload_lds16(Ap + (size_t)128 * 8192, &As[b][8192 + wdst]);
  };
  auto stageB = [&](int b, int kt) {  // 2 gload instrs
    const char* Bp = B + (size_t)(n0 + srow) * 8192 + kt + scol;
    gload_lds16(Bp, &Bs[b][wdst]);
    gload_lds16(Bp + (size_t)128 * 8192, &Bs[b][8192 + wdst]);
  };

  const int nt = 64;  // 4096 / 64
  // prologue: tiles 0 and 1 in flight (8 instrs); validate tile 0 (keep
  // tile 1's 4 outstanding).
  stageA(0, kz);      stageB(0, kz);
  stageA(1, kz + 64); stageB(1, kz + 64);
  asm volatile("s_waitcnt vmcnt(4)\ns_barrier" ::: "memory");

  int cur = 0;
  for (int t = 0; t < nt; ++t) {
    const int nxt = (cur + 2 >= 3) ? cur - 1 : cur + 2;  // (t+2)%3

    // ---- phase 0: B-frags + A-quadrant 0 (mi 0..3); stage A of tile t+2 ----
    i32x4 bf[4], a0[4];
#pragma unroll
    for (int ni = 0; ni < 4; ++ni)
      bf[ni] = *(const i32x4*)&Bs[cur][(wn * 64 + ni * 16 + lrow) * 64 + q16];
#pragma unroll
    for (int mi = 0; mi < 4; ++mi)
      a0[mi] = *(const i32x4*)&As[cur][(wm * 128 + mi * 16 + lrow) * 64 + q16];
    if (t + 2 < nt) stageA(nxt, kz + (t + 2) * 64);
    asm volatile("s_barrier" ::: "memory");
    __builtin_amdgcn_s_setprio(1);
#pragma unroll
    for (int mi = 0; mi < 4; ++mi)
#pragma unroll
      for (int ni = 0; ni < 4; ++ni)
        acc[mi][ni] =
            __builtin_amdgcn_mfma_i32_16x16x64_i8(a0[mi], bf[ni], acc[mi][ni], 0, 0, 0);
    __builtin_amdgcn_s_setprio(0);
    asm volatile("s_barrier" ::: "memory");

    // ---- phase 1: A-quadrant 1 (mi 4..7); stage B of tile t+2 ----
    i32x4 a1[4];
#pragma unroll
    for (int mi = 0; mi < 4; ++mi)
      a1[mi] = *(const i32x4*)&As[cur][(wm * 128 + (mi + 4) * 16 + lrow) * 64 + q16];
    if (t + 2 < nt) stageB(nxt, kz + (t + 2) * 64);
    asm volatile("s_barrier" ::: "memory");
    __builtin_amdgcn_s_setprio(1);
#pragma unroll
    for (int mi = 0; mi < 4; ++mi)
#pragma unroll
      for (int ni = 0; ni < 4; ++ni)
        acc[mi + 4][ni] =
            __builtin_amdgcn_mfma_i32_16x16x64_i8(a1[mi], bf[ni], acc[mi + 4][ni], 0, 0, 0);
    __builtin_amdgcn_s_setprio(0);
    // validate tile t+1 before the barrier that precedes its first reads:
    // outstanding = tile t+1 (4) + tile t+2 (4 if staged) -> keep newest 4.
    if (t + 2 < nt) {
      asm volatile("s_waitcnt vmcnt(4)\ns_barrier" ::: "memory");
    } else if (t + 1 < nt) {
      asm volatile("s_waitcnt vmcnt(0)\ns_barrier" ::: "memory");
    } else {
      asm volatile("s_barrier" ::: "memory");
    }

    cur = (cur + 1 >= 3) ? 0 : cur + 1;
  }

  // split-K reduce: atomic f32 accumulate into pre-zeroed out. No fences.
  const float sc = (*s2p) * (1.f / 15.f) * (1.f / 127.f);
  const int qr = (lane >> 4) * 4;
#pragma unroll
  for (int mi = 0; mi < 8; ++mi) {
    const int mb = m0 + wm * 128 + mi * 16 + qr;
#pragma unroll
    for (int ni = 0; ni < 4; ++ni) {
      const int n = n0 + wn * 64 + ni * 16 + lrow;
#pragma unroll
      for (int r = 0; r < 4; ++r)
        atomicAdd(&outp[(size_t)(mb + r) * 1024 + n], (float)acc[mi][ni][r] * sc);
    }
  }
}

extern "C" void kernel_launch(void* const* d_in, const int* in_sizes, int n_in,
                              void* d_out, int out_size, void* d_ws, size_t ws_size,
                              hipStream_t stream) {
  const float* input  = (const float*)d_in[0];   // 8192 x 1024
  const float* adj    = (const float*)d_in[1];   // 8192 x 8192
  // d_in[2] adj_scaling_factor = 2.0: pow2, cancels exactly in f32
  const float* weight = (const float*)d_in[3];   // 1024 x 1024
  const float* wgt_alpha  = (const float*)d_in[4];
  const float* act_alpha  = (const float*)d_in[5];
  const float* act_alpha2 = (const float*)d_in[6];
  float* out = (float*)d_out;                    // 8192 x 1024 f32

  constexpr int NN = 8192, INF = 1024, OUTF = 1024;
  constexpr size_t MB = 1024 * 1024;
  constexpr size_t HDR = 64 * 1024;

  char* ws = (char*)d_ws;
  double* stats = (double*)ws;                   // 16 B
  char* WtI  = ws + HDR;                         // OUTF x INF   (1 MB)
  char* XqI  = ws + HDR + 1 * MB;                // NN x INF     (8 MB)
  char* StI  = ws + HDR + 9 * MB;                // OUTF x NN    (8 MB)
  char* AdjQ = ws + HDR + 17 * MB;               // NN x NN      (64 MB)
  const size_t need = HDR + 81 * MB;

  hipMemsetAsync(stats, 0, 256, stream);

  // pre: wstats | xquant | out-zero (atomic-reduce destination)
  pre_kernel<<<256 + 4096 + 2048, 256, 0, stream>>>(
      weight, stats, input, XqI, act_alpha, out, INF * OUTF, NN * INF);
  wquant_kernel<<<(INF * OUTF) / 256, 256, 0, stream>>>(weight, WtI, stats, wgt_alpha);

  if (ws_size >= need) {
    // GEMM1: Xq[8192x1024] @ Wt[1024x1024]^T -> Sq^T i8 [1024 x 8192], with
    // adjq (256 MB read / 64 MB write) riding the same dispatch on z=1.
    gemm1_adjq_kernel<<<dim3(NN / 128, OUTF / 128, 2), 256, 0, stream>>>(
        XqI, WtI, StI, act_alpha, wgt_alpha, act_alpha2, adj, AdjQ, (long long)NN * NN);
    // GEMM2: fine-interleaved 256^2 pipeline, split-K x2, atomic f32 reduce.
    gemm2_pipe_kernel<<<dim3(NN / 256, OUTF / 256, 2), 512, 0, stream>>>(
        AdjQ, StI, out, act_alpha2);
  } else {
    gemm_i8_kernel<true, false><<<dim3(NN / 128, OUTF / 128, 1), 256, 0, stream>>>(
        XqI, WtI, StI, nullptr, NN, OUTF, INF, INF,
        act_alpha, wgt_alpha, act_alpha2);
    gemm_i8_kernel<false, true><<<dim3(NN / 128, OUTF / 128, 2), 256, 0, stream>>>(
        adj, StI, nullptr, out, NN, OUTF, NN, NN / 2, nullptr, nullptr, act_alpha2);
  }
}